// Round 8
// baseline (230.149 us; speedup 1.0000x reference)
//
#include <hip/hip_runtime.h>
#include <hip/hip_bf16.h>
#include <cstdint>

#define NN 384
#define OUT1OFF 196608
#define OUT2OFF 205824

typedef float f4 __attribute__((ext_vector_type(4)));
typedef short short8 __attribute__((ext_vector_type(8)));
typedef unsigned int u32;

union FragU { short8 s; u32 w[4]; };

__device__ inline unsigned short f2bf(float f) {
    u32 u = __float_as_uint(f);
    return (unsigned short)((u + 0x7fffu + ((u >> 16) & 1u)) >> 16);
}
__device__ inline u32 pkbf(float lo, float hi) {
    u32 r;
    asm("v_cvt_pk_bf16_f32 %0, %1, %2" : "=v"(r) : "v"(lo), "v"(hi));
    return r;
}
__device__ inline float siluf(float x) {
    return x * __builtin_amdgcn_rcpf(1.0f + __expf(-x));
}
__device__ inline float seluf(float x) {
    const float sc = 1.0507009873554805f, al = 1.6732632423543772f;
    return x > 0.f ? sc * x : sc * al * (__expf(x) - 1.f);
}

#define DSFENCE() do { asm volatile("s_waitcnt lgkmcnt(0)" ::: "memory"); \
                       __builtin_amdgcn_sched_barrier(0); } while (0)

// ---- prep1: HiC[row,h] = be1[h] + feats[row,:]@We1[0:64,h]
//            HjC[row,h] =          feats[row,:]@We1[64:128,h]
__global__ __launch_bounds__(128) void egnn_prep1(
    const float* __restrict__ feats, const float* __restrict__ We1,
    const float* __restrict__ be1, float* __restrict__ HiC, float* __restrict__ HjC) {
    int r0 = blockIdx.x * 8;
    int t = threadIdx.x;
    __shared__ float fr[8][64];
    for (int k = t; k < 512; k += 128) fr[k >> 6][k & 63] = feats[(size_t)r0 * 64 + k];
    __syncthreads();
    float a1[8], a2[8];
#pragma unroll
    for (int r = 0; r < 8; r++) { a1[r] = be1[t]; a2[r] = 0.f; }
    for (int d = 0; d < 64; d++) {
        float w1 = We1[d * 128 + t], w2 = We1[(64 + d) * 128 + t];
#pragma unroll
        for (int r = 0; r < 8; r++) { a1[r] += fr[r][d] * w1; a2[r] += fr[r][d] * w2; }
    }
#pragma unroll
    for (int r = 0; r < 8; r++) {
        HiC[(size_t)(r0 + r) * 128 + t] = a1[r];
        HjC[(size_t)(r0 + r) * 128 + t] = a2[r];
    }
}

// ---- prep2: pack We2^T / Wc1^T as K=32 MFMA A-fragments with PERMUTED k-order.
// Stage-2 k-order: h(kk,g,e) = (2*kk + (e>>2))*16 + 4*g + (e&3), so the B operand
// is the register concat of two stage-1 D-tiles (verified D row=4g+r, B k=8g+e).
__global__ __launch_bounds__(64) void egnn_prep2(
    const float* __restrict__ We2, const float* __restrict__ Wc1,
    unsigned short* __restrict__ B2P, unsigned short* __restrict__ B3P) {
    int f = blockIdx.x;
    int l = threadIdx.x;
    int g = l >> 4, cc = l & 15;
    if (f < 16) {
        int nn = f >> 2, kk = f & 3;
#pragma unroll
        for (int e = 0; e < 8; e++) {
            int h = (2 * kk + (e >> 2)) * 16 + 4 * g + (e & 3);
            B2P[(f * 64 + l) * 8 + e] = f2bf(We2[h * 64 + nn * 16 + cc]);
        }
    } else {
        int f2 = f - 16;
        int mm = f2 >> 1, kk2 = f2 & 1;
#pragma unroll
        for (int e = 0; e < 8; e++) {
            int hm = (2 * kk2 + (e >> 2)) * 16 + 4 * g + (e & 3);
            B3P[(f2 * 64 + l) * 8 + e] = f2bf(Wc1[hm * 64 + mm * 16 + cc]);
        }
    }
}

// ---- main: 4 waves/block; waves (2p,2p+1) split node p's j-tiles 12/12.
// Stage-2 weights in block-shared LDS (read-only, no loop barriers); stage-1/3
// weights in registers. Fence-free register dataflow in the loop.
__global__ __launch_bounds__(256, 4) void egnn_main(
    const float* __restrict__ feats, const float* __restrict__ coors,
    const float* __restrict__ vel, const float* __restrict__ edges,
    const float* __restrict__ We1,
    const float* __restrict__ be2, const float* __restrict__ bc1,
    const float* __restrict__ Wc2, const float* __restrict__ bc2,
    const float* __restrict__ Wn1, const float* __restrict__ bn1,
    const float* __restrict__ Wn2, const float* __restrict__ bn2,
    const float* __restrict__ Wv, const float* __restrict__ bv,
    const float* __restrict__ HiC, const float* __restrict__ HjC,
    const unsigned short* __restrict__ B2P, const unsigned short* __restrict__ B3P,
    float* __restrict__ out) {
    __shared__ __align__(16) unsigned short W2L[8192]; // stage-2 frags, 16KB shared
    __shared__ __align__(16) float epi[4][72];    // per-wave partials: m_i[64], agg[3]
    __shared__ __align__(16) float work[2][256];  // per-node red[128]+hid[128]

    const int tid = threadIdx.x;
    const int w = tid >> 6, lane = tid & 63;
    const int g = lane >> 4, c = lane & 15;

    // stage weight frags to LDS once (no other LDS writes before loop)
    {
        const uint4* s2 = (const uint4*)B2P;
        uint4* d2 = (uint4*)W2L;
#pragma unroll
        for (int k = 0; k < 4; k++) d2[tid + 256 * k] = s2[tid + 256 * k];
    }

    // XCD-bijective swizzle: XCD k owns batch k (HjC 196KB stays L2-resident).
    const int blk = blockIdx.x;
    const int b = blk & 7;
    const int node = (blk >> 3) * 2 + (w >> 1);
    const int jt0 = (w & 1) * 12;
    const int flat = b * NN + node;
    const size_t bi = (size_t)flat;

    // ---- stage-3 weight fragments in registers (32 VGPR)
    FragU b3f[4][2];
#pragma unroll
    for (int mm = 0; mm < 4; mm++)
#pragma unroll
        for (int kk2 = 0; kk2 < 2; kk2++)
            b3f[mm][kk2].s = *(const short8*)(B3P + ((mm * 2 + kk2) * 64 + lane) * 8);

    // ---- stage-1 A-frags: k=0..4 = We1 rows 128..132 (d2,e0..3), k=5 = HiC[i][h]
    u32 w1p0[8], w1p1[8], w1p2[8];
#pragma unroll
    for (int n = 0; n < 8; n++) {
        float v0 = 0.f, v1 = 0.f, v2 = 0.f, v3 = 0.f, v4 = 0.f, v5 = 0.f;
        if (g == 0) {
            const int h = n * 16 + c;
            v0 = We1[128 * 128 + h]; v1 = We1[129 * 128 + h];
            v2 = We1[130 * 128 + h]; v3 = We1[131 * 128 + h];
            v4 = We1[132 * 128 + h];
            v5 = HiC[bi * 128 + h];
        }
        w1p0[n] = pkbf(v0, v1);
        w1p1[n] = pkbf(v2, v3);
        w1p2[n] = pkbf(v4, v5);
    }

    const float bc2v = bc2[0];
    const float ci0 = coors[bi * 3], ci1 = coors[bi * 3 + 1], ci2 = coors[bi * 3 + 2];
    const float cig = (g == 0) ? ci0 : ((g == 1) ? ci1 : ci2);

    f4 maccv[4];
#pragma unroll
    for (int n = 0; n < 4; n++) maccv[n] = (f4){0.f, 0.f, 0.f, 0.f};
    float aggp = 0.f;

    // prefetch this wave's first tile edge/coors
    f4 ev = *(const f4*)&edges[(bi * NN + jt0 * 16 + c) * 4];
    const float* cjp0 = &coors[((size_t)b * NN + jt0 * 16 + c) * 3];
    float cjn0 = cjp0[0], cjn1 = cjp0[1], cjn2 = cjp0[2];

    __syncthreads();   // W2L staged

#pragma unroll 1
    for (int jt = jt0; jt < jt0 + 12; ++jt) {
        const f4 evc = ev;
        const float cj0 = cjn0, cj1 = cjn1, cj2 = cjn2;
        const int jn = (jt + 1 < jt0 + 12) ? (jt + 1) * 16 + c : c;
        ev = *(const f4*)&edges[(bi * NN + jn) * 4];
        const float* cjp = &coors[((size_t)b * NN + jn) * 3];
        cjn0 = cjp[0]; cjn1 = cjp[1]; cjn2 = cjp[2];

        const int j = jt * 16 + c;
        const float* hjp = &HjC[((size_t)b * NN + j) * 128];
        const float r0 = ci0 - cj0, r1 = ci1 - cj1, r2 = ci2 - cj2;
        const float d2v = r0 * r0 + r1 * r1 + r2 * r2;

        FragU b1;
        b1.w[0] = (g == 0) ? pkbf(d2v, evc.x) : 0u;
        b1.w[1] = (g == 0) ? pkbf(evc.y, evc.z) : 0u;
        b1.w[2] = (g == 0) ? pkbf(evc.w, 1.0f) : 0u;
        b1.w[3] = 0u;

        // ---- stage 1: pre = W5~·x~ (+HjC C-init); silu; concat pairs into B-frags
        FragU bf[4];
#pragma unroll
        for (int n = 0; n < 8; n++) {
            FragU a1;
            a1.w[0] = w1p0[n]; a1.w[1] = w1p1[n]; a1.w[2] = w1p2[n]; a1.w[3] = 0u;
            const f4 hcn = *(const f4*)&hjp[n * 16 + 4 * g];
            f4 d1 = __builtin_amdgcn_mfma_f32_16x16x32_bf16(a1.s, b1.s, hcn, 0, 0, 0);
            const int kk = n >> 1, ws = (n & 1) * 2;
            bf[kk].w[ws]     = pkbf(siluf(d1.x), siluf(d1.y));
            bf[kk].w[ws + 1] = pkbf(siluf(d1.z), siluf(d1.w));
        }

        // ---- stage 2: M2 = We2~ · m1 (+be2 C-init) — weights from shared LDS
        f4 c2[4];
#pragma unroll
        for (int nn = 0; nn < 4; nn++) c2[nn] = *(const f4*)&be2[nn * 16 + 4 * g];
#pragma unroll
        for (int kk = 0; kk < 4; kk++)
#pragma unroll
            for (int nn = 0; nn < 4; nn++) {
                const short8 wf = *(const short8*)&W2L[(nn * 4 + kk) * 512 + lane * 8];
                c2[nn] = __builtin_amdgcn_mfma_f32_16x16x32_bf16(wf, bf[kk].s, c2[nn], 0, 0, 0);
            }

        FragU bt[2];
#pragma unroll
        for (int nn = 0; nn < 4; nn++) {
            f4 s2;
            s2.x = siluf(c2[nn].x); s2.y = siluf(c2[nn].y);
            s2.z = siluf(c2[nn].z); s2.w = siluf(c2[nn].w);
            maccv[nn] += s2;
            const int kk2 = nn >> 1, ws = (nn & 1) * 2;
            bt[kk2].w[ws]     = pkbf(s2.x, s2.y);
            bt[kk2].w[ws + 1] = pkbf(s2.z, s2.w);
        }

        // ---- stage 3: cwh = Wc1~ · m (+bc1 C-init); cw = silu(cwh)·Wc2 + bc2
        f4 c3[4];
#pragma unroll
        for (int mm = 0; mm < 4; mm++) c3[mm] = *(const f4*)&bc1[mm * 16 + 4 * g];
#pragma unroll
        for (int kk2 = 0; kk2 < 2; kk2++)
#pragma unroll
            for (int mm = 0; mm < 4; mm++)
                c3[mm] = __builtin_amdgcn_mfma_f32_16x16x32_bf16(b3f[mm][kk2].s, bt[kk2].s, c3[mm], 0, 0, 0);

        float cwp = 0.f;
#pragma unroll
        for (int mm = 0; mm < 4; mm++) {
            const f4 wc = *(const f4*)&Wc2[mm * 16 + 4 * g];
            cwp += siluf(c3[mm].x) * wc.x;
            cwp += siluf(c3[mm].y) * wc.y;
            cwp += siluf(c3[mm].z) * wc.z;
            cwp += siluf(c3[mm].w) * wc.w;
        }
        cwp += __shfl_xor(cwp, 16);
        cwp += __shfl_xor(cwp, 32);
        const float cw = cwp + bc2v;
        const float cjg = (g == 0) ? cj0 : ((g == 1) ? cj1 : cj2);
        aggp += (cig - cjg) * cw;   // valid for g<3; g==3 partial never read
    }

    // ---- fold this wave's partials and publish
#pragma unroll
    for (int n = 0; n < 4; n++) {
#pragma unroll
        for (int r = 0; r < 4; r++) {
            float v = maccv[n][r];
            v += __shfl_xor(v, 1); v += __shfl_xor(v, 2);
            v += __shfl_xor(v, 4); v += __shfl_xor(v, 8);
            maccv[n][r] = v;
        }
    }
    float aggr = aggp;
    aggr += __shfl_xor(aggr, 1); aggr += __shfl_xor(aggr, 2);
    aggr += __shfl_xor(aggr, 4); aggr += __shfl_xor(aggr, 8);

    if (c == 0) {
#pragma unroll
        for (int n = 0; n < 4; n++)
            *(f4*)&epi[w][n * 16 + 4 * g] = maccv[n];
        if (g < 3) epi[w][64 + g] = aggr;
    }
    __syncthreads();

    // ---- merged epilogue: even wave of each pair finishes its node
    if ((w & 1) == 0) {
        float* red = &work[w >> 1][0];
        float* hid = red + 128;

        const float mi = epi[w][lane] + epi[w + 1][lane];
        const int gc = (g < 3) ? g : 0;
        const float ag = epi[w][64 + gc] + epi[w + 1][64 + gc];

        const float fv = feats[bi * 64 + lane];
        float gp = fv * Wv[lane];
        gp += __shfl_xor(gp, 1);  gp += __shfl_xor(gp, 2);
        gp += __shfl_xor(gp, 4);  gp += __shfl_xor(gp, 8);
        gp += __shfl_xor(gp, 16); gp += __shfl_xor(gp, 32);
        const float sgate = gp + bv[0];

        red[lane] = fv;
        red[64 + lane] = mi;
        DSFENCE();

        // node MLP: hid = silu([h|m_i]@Wn1+bn1); out = h + hid@Wn2+bn2
        float a0 = bn1[lane], a1 = bn1[64 + lane];
#pragma unroll 4
        for (int k0 = 0; k0 < 128; k0 += 4) {
            const f4 rv = *(const f4*)&red[k0];
#pragma unroll
            for (int kk = 0; kk < 4; kk++) {
                const float* wr = &Wn1[(size_t)(k0 + kk) * 128];
                a0 += rv[kk] * wr[lane];
                a1 += rv[kk] * wr[64 + lane];
            }
        }
        hid[lane] = siluf(a0);
        hid[64 + lane] = siluf(a1);
        DSFENCE();
        float o = bn2[lane];
#pragma unroll 4
        for (int k0 = 0; k0 < 128; k0 += 4) {
            const f4 hv = *(const f4*)&hid[k0];
#pragma unroll
            for (int kk = 0; kk < 4; kk++)
                o += hv[kk] * Wn2[(size_t)(k0 + kk) * 64 + lane];
        }
        out[bi * 64 + lane] = fv + o;

        if (c == 0 && g < 3) {
            const size_t base = bi * 3 + g;
            const float vn = sgate * vel[base] + ag * (1.f / 384.f);
            const float cn = coors[base] + vn;
            out[OUT1OFF + base] = seluf(cn);
            out[OUT2OFF + base] = seluf(vn);
        }
    }
}

extern "C" void kernel_launch(void* const* d_in, const int* in_sizes, int n_in,
                              void* d_out, int out_size, void* d_ws, size_t ws_size,
                              hipStream_t stream) {
    const float* feats = (const float*)d_in[0];
    const float* coors = (const float*)d_in[1];
    const float* vel   = (const float*)d_in[2];
    const float* edges = (const float*)d_in[3];
    const float* We1   = (const float*)d_in[4];
    const float* be1   = (const float*)d_in[5];
    const float* We2   = (const float*)d_in[6];
    const float* be2   = (const float*)d_in[7];
    const float* Wc1   = (const float*)d_in[8];
    const float* bc1   = (const float*)d_in[9];
    const float* Wc2   = (const float*)d_in[10];
    const float* bc2   = (const float*)d_in[11];
    const float* Wn1   = (const float*)d_in[12];
    const float* bn1   = (const float*)d_in[13];
    const float* Wn2   = (const float*)d_in[14];
    const float* bn2   = (const float*)d_in[15];
    const float* Wv    = (const float*)d_in[16];
    const float* bv    = (const float*)d_in[17];

    float* HiC = (float*)d_ws;                              // 393216 f32
    float* HjC = HiC + 393216;                              // 393216 f32
    unsigned short* B2P = (unsigned short*)(HjC + 393216);  // 8192 u16
    unsigned short* B3P = B2P + 8192;                       // 4096 u16
    float* out = (float*)d_out;

    egnn_prep1<<<384, 128, 0, stream>>>(feats, We1, be1, HiC, HjC);
    egnn_prep2<<<24, 64, 0, stream>>>(We2, Wc1, B2P, B3P);
    egnn_main<<<1536, 256, 0, stream>>>(feats, coors, vel, edges, We1,
                                        be2, bc1, Wc2, bc2, Wn1, bn1, Wn2, bn2,
                                        Wv, bv, HiC, HjC, B2P, B3P, out);
}

// Round 9
// 138.786 us; speedup vs baseline: 1.6583x; 1.6583x over previous
//
#include <hip/hip_runtime.h>
#include <hip/hip_bf16.h>
#include <cstdint>

#define NN 384
#define OUT1OFF 196608
#define OUT2OFF 205824

typedef float f4 __attribute__((ext_vector_type(4)));
typedef short short8 __attribute__((ext_vector_type(8)));
typedef unsigned int u32;

union FragU { short8 s; u32 w[4]; };

__device__ inline unsigned short f2bf(float f) {
    u32 u = __float_as_uint(f);
    return (unsigned short)((u + 0x7fffu + ((u >> 16) & 1u)) >> 16);
}
__device__ inline u32 pkbf(float lo, float hi) {
    u32 r;
    asm("v_cvt_pk_bf16_f32 %0, %1, %2" : "=v"(r) : "v"(lo), "v"(hi));
    return r;
}
__device__ inline float siluf(float x) {
    return x * __builtin_amdgcn_rcpf(1.0f + __expf(-x));
}
__device__ inline float seluf(float x) {
    const float sc = 1.0507009873554805f, al = 1.6732632423543772f;
    return x > 0.f ? sc * x : sc * al * (__expf(x) - 1.f);
}

#define DSFENCE() do { asm volatile("s_waitcnt lgkmcnt(0)" ::: "memory"); \
                       __builtin_amdgcn_sched_barrier(0); } while (0)

// ---- prep1: HiC[row,h] = be1[h] + feats[row,:]@We1[0:64,h]
//            HjC[row,h] =          feats[row,:]@We1[64:128,h]
__global__ __launch_bounds__(128) void egnn_prep1(
    const float* __restrict__ feats, const float* __restrict__ We1,
    const float* __restrict__ be1, float* __restrict__ HiC, float* __restrict__ HjC) {
    int r0 = blockIdx.x * 8;
    int t = threadIdx.x;
    __shared__ float fr[8][64];
    for (int k = t; k < 512; k += 128) fr[k >> 6][k & 63] = feats[(size_t)r0 * 64 + k];
    __syncthreads();
    float a1[8], a2[8];
#pragma unroll
    for (int r = 0; r < 8; r++) { a1[r] = be1[t]; a2[r] = 0.f; }
    for (int d = 0; d < 64; d++) {
        float w1 = We1[d * 128 + t], w2 = We1[(64 + d) * 128 + t];
#pragma unroll
        for (int r = 0; r < 8; r++) { a1[r] += fr[r][d] * w1; a2[r] += fr[r][d] * w2; }
    }
#pragma unroll
    for (int r = 0; r < 8; r++) {
        HiC[(size_t)(r0 + r) * 128 + t] = a1[r];
        HjC[(size_t)(r0 + r) * 128 + t] = a2[r];
    }
}

// ---- prep2: pack We2^T / Wc1^T as K=32 MFMA A-fragments with PERMUTED k-order.
// Stage-2 k-order: h(kk,g,e) = (2*kk + (e>>2))*16 + 4*g + (e&3), so the B operand
// is the register concat of two stage-1 D-tiles (verified D row=4g+r, B k=8g+e).
__global__ __launch_bounds__(64) void egnn_prep2(
    const float* __restrict__ We2, const float* __restrict__ Wc1,
    unsigned short* __restrict__ B2P, unsigned short* __restrict__ B3P) {
    int f = blockIdx.x;
    int l = threadIdx.x;
    int g = l >> 4, cc = l & 15;
    if (f < 16) {
        int nn = f >> 2, kk = f & 3;
#pragma unroll
        for (int e = 0; e < 8; e++) {
            int h = (2 * kk + (e >> 2)) * 16 + 4 * g + (e & 3);
            B2P[(f * 64 + l) * 8 + e] = f2bf(We2[h * 64 + nn * 16 + cc]);
        }
    } else {
        int f2 = f - 16;
        int mm = f2 >> 1, kk2 = f2 & 1;
#pragma unroll
        for (int e = 0; e < 8; e++) {
            int hm = (2 * kk2 + (e >> 2)) * 16 + 4 * g + (e & 3);
            B3P[(f2 * 64 + l) * 8 + e] = f2bf(Wc1[hm * 64 + mm * 16 + cc]);
        }
    }
}

// ---- main: 4 waves/block, one wave per node, 24 j-tiles each.
// ALL per-edge weights live in block LDS (read-only, staged once, no loop
// barriers); loop dataflow is the fence-free permuted-k register chain.
__global__ __launch_bounds__(256, 4) void egnn_main(
    const float* __restrict__ feats, const float* __restrict__ coors,
    const float* __restrict__ vel, const float* __restrict__ edges,
    const float* __restrict__ We1,
    const float* __restrict__ be2, const float* __restrict__ bc1,
    const float* __restrict__ Wc2, const float* __restrict__ bc2,
    const float* __restrict__ Wn1, const float* __restrict__ bn1,
    const float* __restrict__ Wn2, const float* __restrict__ bn2,
    const float* __restrict__ Wv, const float* __restrict__ bv,
    const float* __restrict__ HiC, const float* __restrict__ HjC,
    const unsigned short* __restrict__ B2P, const unsigned short* __restrict__ B3P,
    float* __restrict__ out) {
    __shared__ __align__(16) unsigned short W2L[8192];  // 16 KB stage-2 frags
    __shared__ __align__(16) unsigned short W3L[4096];  // 8 KB stage-3 frags
    __shared__ __align__(16) float work[4][256];        // per-wave red[128]+hid[128]

    const int tid = threadIdx.x;
    const int w = tid >> 6, lane = tid & 63;
    const int g = lane >> 4, c = lane & 15;

    // stage weight frags to LDS once
    {
        const uint4* s2 = (const uint4*)B2P;
        uint4* d2 = (uint4*)W2L;
#pragma unroll
        for (int k = 0; k < 4; k++) d2[tid + 256 * k] = s2[tid + 256 * k];
        const uint4* s3 = (const uint4*)B3P;
        uint4* d3 = (uint4*)W3L;
#pragma unroll
        for (int k = 0; k < 2; k++) d3[tid + 256 * k] = s3[tid + 256 * k];
    }

    // XCD-bijective swizzle: XCD k owns batch k (HjC 196KB stays L2-resident)
    const int blk = blockIdx.x;
    const int b = blk & 7;
    const int node = (blk >> 3) * 4 + w;
    const int flat = b * NN + node;
    const size_t bi = (size_t)flat;

    // ---- stage-1 A-frags: k=0..4 = We1 rows 128..132 (d2,e0..3), k=5 = HiC[i][h]
    u32 w1p0[8], w1p1[8], w1p2[8];
#pragma unroll
    for (int n = 0; n < 8; n++) {
        float v0 = 0.f, v1 = 0.f, v2 = 0.f, v3 = 0.f, v4 = 0.f, v5 = 0.f;
        if (g == 0) {
            const int h = n * 16 + c;
            v0 = We1[128 * 128 + h]; v1 = We1[129 * 128 + h];
            v2 = We1[130 * 128 + h]; v3 = We1[131 * 128 + h];
            v4 = We1[132 * 128 + h];
            v5 = HiC[bi * 128 + h];
        }
        w1p0[n] = pkbf(v0, v1);
        w1p1[n] = pkbf(v2, v3);
        w1p2[n] = pkbf(v4, v5);
    }

    const float bc2v = bc2[0];
    const float ci0 = coors[bi * 3], ci1 = coors[bi * 3 + 1], ci2 = coors[bi * 3 + 2];
    const float cig = (g == 0) ? ci0 : ((g == 1) ? ci1 : ci2);

    f4 maccv[4];
#pragma unroll
    for (int n = 0; n < 4; n++) maccv[n] = (f4){0.f, 0.f, 0.f, 0.f};
    float aggp = 0.f;

    // prefetch tile 0 edge/coors
    f4 ev = *(const f4*)&edges[(bi * NN + c) * 4];
    const float* cjp0 = &coors[((size_t)b * NN + c) * 3];
    float cjn0 = cjp0[0], cjn1 = cjp0[1], cjn2 = cjp0[2];

    const unsigned short* w2base = &W2L[lane * 8];
    const unsigned short* w3base = &W3L[lane * 8];

    __syncthreads();   // weights staged

#pragma unroll 1
    for (int jt = 0; jt < 24; ++jt) {
        const f4 evc = ev;
        const float cj0 = cjn0, cj1 = cjn1, cj2 = cjn2;
        const int jn = (jt + 1 < 24) ? (jt + 1) * 16 + c : c;
        ev = *(const f4*)&edges[(bi * NN + jn) * 4];
        const float* cjp = &coors[((size_t)b * NN + jn) * 3];
        cjn0 = cjp[0]; cjn1 = cjp[1]; cjn2 = cjp[2];

        const int j = jt * 16 + c;
        const float* hjp = &HjC[((size_t)b * NN + j) * 128];
        const float r0 = ci0 - cj0, r1 = ci1 - cj1, r2 = ci2 - cj2;
        const float d2v = r0 * r0 + r1 * r1 + r2 * r2;

        FragU b1;
        b1.w[0] = (g == 0) ? pkbf(d2v, evc.x) : 0u;
        b1.w[1] = (g == 0) ? pkbf(evc.y, evc.z) : 0u;
        b1.w[2] = (g == 0) ? pkbf(evc.w, 1.0f) : 0u;
        b1.w[3] = 0u;

        // ---- stage 1: pre = W5~·x~ (+HjC C-init); silu; concat pairs into B-frags
        FragU bf[4];
#pragma unroll
        for (int n = 0; n < 8; n++) {
            FragU a1;
            a1.w[0] = w1p0[n]; a1.w[1] = w1p1[n]; a1.w[2] = w1p2[n]; a1.w[3] = 0u;
            const f4 hcn = *(const f4*)&hjp[n * 16 + 4 * g];
            f4 d1 = __builtin_amdgcn_mfma_f32_16x16x32_bf16(a1.s, b1.s, hcn, 0, 0, 0);
            const int kk = n >> 1, ws = (n & 1) * 2;
            bf[kk].w[ws]     = pkbf(siluf(d1.x), siluf(d1.y));
            bf[kk].w[ws + 1] = pkbf(siluf(d1.z), siluf(d1.w));
        }

        // ---- stage 2: M2 = We2~ · m1 (+be2 C-init) — weights from LDS
        f4 c2[4];
#pragma unroll
        for (int nn = 0; nn < 4; nn++) c2[nn] = *(const f4*)&be2[nn * 16 + 4 * g];
#pragma unroll
        for (int kk = 0; kk < 4; kk++)
#pragma unroll
            for (int nn = 0; nn < 4; nn++) {
                const short8 wf = *(const short8*)&w2base[(nn * 4 + kk) * 512];
                c2[nn] = __builtin_amdgcn_mfma_f32_16x16x32_bf16(wf, bf[kk].s, c2[nn], 0, 0, 0);
            }

        FragU bt[2];
#pragma unroll
        for (int nn = 0; nn < 4; nn++) {
            f4 s2;
            s2.x = siluf(c2[nn].x); s2.y = siluf(c2[nn].y);
            s2.z = siluf(c2[nn].z); s2.w = siluf(c2[nn].w);
            maccv[nn] += s2;
            const int kk2 = nn >> 1, ws = (nn & 1) * 2;
            bt[kk2].w[ws]     = pkbf(s2.x, s2.y);
            bt[kk2].w[ws + 1] = pkbf(s2.z, s2.w);
        }

        // ---- stage 3: cwh = Wc1~ · m (+bc1 C-init); cw = silu(cwh)·Wc2 + bc2
        f4 c3[4];
#pragma unroll
        for (int mm = 0; mm < 4; mm++) c3[mm] = *(const f4*)&bc1[mm * 16 + 4 * g];
#pragma unroll
        for (int kk2 = 0; kk2 < 2; kk2++)
#pragma unroll
            for (int mm = 0; mm < 4; mm++) {
                const short8 wf3 = *(const short8*)&w3base[(mm * 2 + kk2) * 512];
                c3[mm] = __builtin_amdgcn_mfma_f32_16x16x32_bf16(wf3, bt[kk2].s, c3[mm], 0, 0, 0);
            }

        float cwp = 0.f;
#pragma unroll
        for (int mm = 0; mm < 4; mm++) {
            const f4 wc = *(const f4*)&Wc2[mm * 16 + 4 * g];
            cwp += siluf(c3[mm].x) * wc.x;
            cwp += siluf(c3[mm].y) * wc.y;
            cwp += siluf(c3[mm].z) * wc.z;
            cwp += siluf(c3[mm].w) * wc.w;
        }
        cwp += __shfl_xor(cwp, 16);
        cwp += __shfl_xor(cwp, 32);
        const float cw = cwp + bc2v;
        const float cjg = (g == 0) ? cj0 : ((g == 1) ? cj1 : cj2);
        aggp += (cig - cjg) * cw;   // valid for g<3; g==3 partial never read
    }

    // ---- per-wave epilogue (wave-local LDS region; lgkmcnt-only ordering)
    float* red = &work[w][0];
    float* hid = red + 128;

#pragma unroll
    for (int n = 0; n < 4; n++) {
#pragma unroll
        for (int r = 0; r < 4; r++) {
            float v = maccv[n][r];
            v += __shfl_xor(v, 1); v += __shfl_xor(v, 2);
            v += __shfl_xor(v, 4); v += __shfl_xor(v, 8);
            maccv[n][r] = v;
        }
    }
    const float fv = feats[bi * 64 + lane];
    float gp = fv * Wv[lane];
    gp += __shfl_xor(gp, 1);  gp += __shfl_xor(gp, 2);
    gp += __shfl_xor(gp, 4);  gp += __shfl_xor(gp, 8);
    gp += __shfl_xor(gp, 16); gp += __shfl_xor(gp, 32);
    const float sgate = gp + bv[0];

    float aggr = aggp;
    aggr += __shfl_xor(aggr, 1); aggr += __shfl_xor(aggr, 2);
    aggr += __shfl_xor(aggr, 4); aggr += __shfl_xor(aggr, 8);

    red[lane] = fv;
    if (c == 0) {
#pragma unroll
        for (int n = 0; n < 4; n++)
            *(f4*)&red[64 + n * 16 + 4 * g] = maccv[n];
    }
    DSFENCE();

    // node MLP: hid = silu([h|m_i]@Wn1+bn1); out = h + hid@Wn2+bn2
    float a0 = bn1[lane], a1 = bn1[64 + lane];
#pragma unroll 4
    for (int k0 = 0; k0 < 128; k0 += 4) {
        const f4 rv = *(const f4*)&red[k0];
#pragma unroll
        for (int kk = 0; kk < 4; kk++) {
            const float* wr = &Wn1[(size_t)(k0 + kk) * 128];
            a0 += rv[kk] * wr[lane];
            a1 += rv[kk] * wr[64 + lane];
        }
    }
    hid[lane] = siluf(a0);
    hid[64 + lane] = siluf(a1);
    DSFENCE();
    float o = bn2[lane];
#pragma unroll 4
    for (int k0 = 0; k0 < 128; k0 += 4) {
        const f4 hv = *(const f4*)&hid[k0];
#pragma unroll
        for (int kk = 0; kk < 4; kk++)
            o += hv[kk] * Wn2[(size_t)(k0 + kk) * 64 + lane];
    }
    out[bi * 64 + lane] = fv + o;

    if (c == 0 && g < 3) {
        const size_t base = bi * 3 + g;
        const float vn = sgate * vel[base] + aggr * (1.f / 384.f);
        const float cn = coors[base] + vn;
        out[OUT1OFF + base] = seluf(cn);
        out[OUT2OFF + base] = seluf(vn);
    }
}

extern "C" void kernel_launch(void* const* d_in, const int* in_sizes, int n_in,
                              void* d_out, int out_size, void* d_ws, size_t ws_size,
                              hipStream_t stream) {
    const float* feats = (const float*)d_in[0];
    const float* coors = (const float*)d_in[1];
    const float* vel   = (const float*)d_in[2];
    const float* edges = (const float*)d_in[3];
    const float* We1   = (const float*)d_in[4];
    const float* be1   = (const float*)d_in[5];
    const float* We2   = (const float*)d_in[6];
    const float* be2   = (const float*)d_in[7];
    const float* Wc1   = (const float*)d_in[8];
    const float* bc1   = (const float*)d_in[9];
    const float* Wc2   = (const float*)d_in[10];
    const float* bc2   = (const float*)d_in[11];
    const float* Wn1   = (const float*)d_in[12];
    const float* bn1   = (const float*)d_in[13];
    const float* Wn2   = (const float*)d_in[14];
    const float* bn2   = (const float*)d_in[15];
    const float* Wv    = (const float*)d_in[16];
    const float* bv    = (const float*)d_in[17];

    float* HiC = (float*)d_ws;                              // 393216 f32
    float* HjC = HiC + 393216;                              // 393216 f32
    unsigned short* B2P = (unsigned short*)(HjC + 393216);  // 8192 u16
    unsigned short* B3P = B2P + 8192;                       // 4096 u16
    float* out = (float*)d_out;

    egnn_prep1<<<384, 128, 0, stream>>>(feats, We1, be1, HiC, HjC);
    egnn_prep2<<<24, 64, 0, stream>>>(We2, Wc1, B2P, B3P);
    egnn_main<<<768, 256, 0, stream>>>(feats, coors, vel, edges, We1,
                                       be2, bc1, Wc2, bc2, Wn1, bn1, Wn2, bn2,
                                       Wv, bv, HiC, HjC, B2P, B3P, out);
}